// Round 7
// baseline (1264.073 us; speedup 1.0000x reference)
//
#include <hip/hip_runtime.h>
#include <math.h>

typedef __attribute__((ext_vector_type(8))) short short8;
typedef __attribute__((ext_vector_type(4))) float floatx4;

__device__ __forceinline__ float bits2f(short u) {
  unsigned int x = ((unsigned int)(unsigned short)u) << 16;
  return __builtin_bit_cast(float, x);
}
__device__ __forceinline__ short f2bits(float f) {
  unsigned int x = __builtin_bit_cast(unsigned int, f);
  x += 0x7FFFu + ((x >> 16) & 1u);   // RNE
  return (short)(x >> 16);
}

// Load one MFMA A/B fragment (8 K-contiguous elems). F32: convert in-register.
template <bool F32>
__device__ __forceinline__ short8 load_frag(const void* __restrict__ base, long eoff) {
  if constexpr (F32) {
    const float* p = (const float*)base + eoff;
    floatx4 v0 = *(const floatx4*)p;
    floatx4 v1 = *(const floatx4*)(p + 4);
    short8 o;
#pragma unroll
    for (int e = 0; e < 4; e++) { o[e] = f2bits(v0[e]); o[e + 4] = f2bits(v1[e]); }
    return o;
  } else {
    return *(const short8*)((const short*)base + eoff);
  }
}

// ---------------------------------------------------------------------------
// C[m][n] = sum_k A[m][k]*B[n][k]  (K-contiguous, fp32 acc). COUT_F32 selects
// float or bf16 output. 256 thr = 4 waves (2x2), 128x128 block tile, 64x64
// wave tile, direct-global fragments. K%32==0, M%128==0, N%128==0.
// ---------------------------------------------------------------------------
template <bool AF32, bool BF32, bool COUT_F32>
__global__ __launch_bounds__(256) void gemm_bt(const void* __restrict__ A,
                                               const void* __restrict__ B,
                                               void* __restrict__ C,
                                               int M, int N, int K) {
  const int lane = threadIdx.x & 63;
  const int wave = threadIdx.x >> 6;
  const int frow = lane & 15;
  const int quad = lane >> 4;
  const long m_base = (long)blockIdx.y * 128 + (wave >> 1) * 64;
  const long n_base = (long)blockIdx.x * 128 + (wave & 1) * 64;

  floatx4 acc[4][4];
#pragma unroll
  for (int i = 0; i < 4; i++)
#pragma unroll
    for (int j = 0; j < 4; j++) acc[i][j] = (floatx4){0.f, 0.f, 0.f, 0.f};

  const long a0 = (m_base + frow) * (long)K + quad * 8;
  const long b0 = (n_base + frow) * (long)K + quad * 8;

  for (int k0 = 0; k0 < K; k0 += 32) {
    short8 a[4], b[4];
#pragma unroll
    for (int i = 0; i < 4; i++) a[i] = load_frag<AF32>(A, a0 + (long)i * 16 * K + k0);
#pragma unroll
    for (int i = 0; i < 4; i++) b[i] = load_frag<BF32>(B, b0 + (long)i * 16 * K + k0);
#pragma unroll
    for (int mi = 0; mi < 4; mi++)
#pragma unroll
      for (int ni = 0; ni < 4; ni++)
        acc[mi][ni] = __builtin_amdgcn_mfma_f32_16x16x32_bf16(a[mi], b[ni], acc[mi][ni], 0, 0, 0);
  }

#pragma unroll
  for (int mi = 0; mi < 4; mi++)
#pragma unroll
    for (int ni = 0; ni < 4; ni++) {
      long row0 = m_base + mi * 16 + quad * 4;   // C/D: col=lane&15, row=quad*4+r
      long col  = n_base + ni * 16 + frow;
#pragma unroll
      for (int r = 0; r < 4; r++) {
        if constexpr (COUT_F32)
          ((float*)C)[(row0 + r) * (long)N + col] = acc[mi][ni][r];
        else
          ((short*)C)[(row0 + r) * (long)N + col] = f2bits(acc[mi][ni][r]);
      }
    }
}

// ---------------------------------------------------------------------------
// Scalar attention (construction-verified): 1 wave per (head, chunk, batch);
// thread = query position. qkv bf16 in, y bf16 out.
// ---------------------------------------------------------------------------
__global__ __launch_bounds__(64) void attn_simple(const short* __restrict__ qkv,
                                                  short* __restrict__ y) {
  const int t = threadIdx.x;       // query position within chunk (0..63)
  const int h = blockIdx.x;        // head
  const int chunk = blockIdx.y;
  const int b = blockIdx.z;

  __shared__ float kk[64][65];     // roped k rows  (+1 pad)
  __shared__ float vv[64][65];     // raw v rows

  const long rowbase = (long)b * 4096 + (long)chunk * 64;
  const short* base = qkv + (rowbase + t) * 3072 + h * 64;

  // per-thread rope factors for position t
  float ct[32], st[32];
#pragma unroll
  for (int j = 0; j < 32; j++) {
    float inv = exp2f(-(float)j * 0.41524101186092030f);  // 10000^(-j/32)
    float ang = (float)t * inv;
    st[j] = sinf(ang);
    ct[j] = cosf(ang);
  }

  // q row -> regs (roped, f32)
  float q[64];
  {
    float raw[64];
    for (int d = 0; d < 64; d++) raw[d] = bits2f(base[d]);
#pragma unroll
    for (int c = 0; c < 32; c++) {
      q[c]      = raw[c] * ct[c] + raw[c + 32] * st[c];
      q[c + 32] = raw[c + 32] * ct[c] - raw[c] * st[c];
    }
  }
  // k row -> LDS (roped)
  {
    float raw[64];
    for (int d = 0; d < 64; d++) raw[d] = bits2f(base[1024 + d]);
#pragma unroll
    for (int c = 0; c < 32; c++) {
      kk[t][c]      = raw[c] * ct[c] + raw[c + 32] * st[c];
      kk[t][c + 32] = raw[c + 32] * ct[c] - raw[c] * st[c];
    }
  }
  // v row -> LDS (raw)
  for (int d = 0; d < 64; d++) vv[t][d] = bits2f(base[2048 + d]);

  __syncthreads();

  // scores
  float s[64];
  for (int j = 0; j < 64; j++) {
    float acc = 0.f;
#pragma unroll
    for (int d = 0; d < 64; d++) acc += q[d] * kk[j][d];
    s[j] = acc * 0.125f;   // 1/sqrt(64)
  }
  // softmax (fully in-thread)
  float mx = -3.0e38f;
  for (int j = 0; j < 64; j++) mx = fmaxf(mx, s[j]);
  float sum = 0.f;
  for (int j = 0; j < 64; j++) { s[j] = __expf(s[j] - mx); sum += s[j]; }
  float isum = 1.0f / sum;

  // y row = p @ V
  float o[64];
  for (int d = 0; d < 64; d++) o[d] = 0.f;
  for (int j = 0; j < 64; j++) {
    float pj = s[j] * isum;
#pragma unroll
    for (int d = 0; d < 64; d++) o[d] += pj * vv[j][d];
  }

  // write y row (bf16)
  short* dst = y + (rowbase + t) * 1024 + h * 64;
  for (int d = 0; d < 64; d++) dst[d] = f2bits(o[d]);
}

// ---------------------------------------------------------------------------
extern "C" void kernel_launch(void* const* d_in, const int* in_sizes, int n_in,
                              void* d_out, int out_size, void* d_ws, size_t ws_size,
                              hipStream_t stream) {
  (void)in_sizes; (void)n_in; (void)out_size; (void)ws_size;
  const float* x      = (const float*)d_in[0];  // f32 (4,4096,1024)
  const float* w_attn = (const float*)d_in[1];  // f32 (3072,1024)
  const float* w_proj = (const float*)d_in[2];  // f32 (1024,1024)
  float* out = (float*)d_out;                   // *** f32 *** (4,4096,1024)

  short* qkv = (short*)d_ws;                    // 16384x3072 bf16 = 96 MiB
  short* yb  = qkv + (size_t)16384 * 3072;      // 16384x1024 bf16 = 32 MiB

  // qkv = x @ w_attn^T   (f32 in -> bf16 frags -> bf16 qkv)
  gemm_bt<true, true, false><<<dim3(24, 128), 256, 0, stream>>>(x, w_attn, qkv, 16384, 3072, 1024);
  // chunked attention -> y (bf16, ws)
  attn_simple<<<dim3(16, 64, 4), 64, 0, stream>>>(qkv, yb);
  // out = y @ w_proj^T   (f32 OUTPUT)
  gemm_bt<false, true, true><<<dim3(8, 128), 256, 0, stream>>>(yb, w_proj, out, 16384, 1024, 1024);
}